// Round 1
// baseline (237.825 us; speedup 1.0000x reference)
//
#include <hip/hip_runtime.h>

#define NCLS 19
#define HW (512 * 512)
#define NPIX (8 * HW)

__device__ __forceinline__ float fexp(float x) { return __expf(x); }
__device__ __forceinline__ float flog(float x) { return __logf(x); }

__global__ __launch_bounds__(256) void lms_main_kernel(
    const float* __restrict__ logits, const int* __restrict__ labels,
    float* __restrict__ ws) {
  const float COEFF = 1.0f / 18.0f;   // 1/(C-1)
  const float LAM_HALF = 0.15f;       // 0.3 / 2

  int t = blockIdx.x * blockDim.x + threadIdx.x;
  long p = (long)t * 4;  // first pixel of this thread's quad

  float loss = 0.0f;
  float cnt = 0.0f;

  if (p < NPIX) {
    int n = (int)(p / HW);
    int hw = (int)(p % HW);
    const float* base = logits + (size_t)n * NCLS * HW + hw;

    // 4 labels for the quad (16B aligned: p%4==0)
    int4 lb4 = *(const int4*)(labels + p);
    int lbs[4] = {lb4.x, lb4.y, lb4.z, lb4.w};

    // Load all 19 channels x 4 pixels: 19 dwordx4 loads, coalesced across wave
    float4 x[NCLS];
#pragma unroll
    for (int c = 0; c < NCLS; ++c)
      x[c] = *(const float4*)(base + (size_t)c * HW);

#pragma unroll
    for (int j = 0; j < 4; ++j) {
      float xv[NCLS];
#pragma unroll
      for (int c = 0; c < NCLS; ++c) xv[c] = ((const float*)&x[c])[j];

      int lb = lbs[j];
      bool valid = (lb != 255);
      int l = valid ? lb : 0;

      // overall max
      float M = xv[0];
#pragma unroll
      for (int c = 1; c < NCLS; ++c) M = fmaxf(M, xv[c]);

      // full and masked sum-of-exp with the same shift
      float s_all = 0.0f;
#pragma unroll
      for (int c = 0; c < NCLS; ++c) s_all += fexp(xv[c] - M);
      float x_l = xv[l];
      float e_l = fexp(x_l - M);
      float s_m = s_all - e_l;

      float lse = M + flog(s_all);      // logsumexp(all)
      float lse_m = M + flog(s_m);      // logsumexp(non-label)
      float inv_sm = 1.0f / s_m;

      // margin term: sum_{c != l} (q_c - coeff) * log q_c
      float msum = 0.0f;
#pragma unroll
      for (int c = 0; c < NCLS; ++c) {
        float e = fexp(xv[c] - M);
        float term = (e * inv_sm - COEFF) * (xv[c] - lse_m);
        msum += (c == l) ? 0.0f : term;
      }

      float ce = lse - x_l;
      float pixel_loss = ce + LAM_HALF * msum;
      loss += valid ? pixel_loss : 0.0f;
      cnt += valid ? 1.0f : 0.0f;
    }
  }

  // wave (64-lane) shuffle reduction
#pragma unroll
  for (int off = 32; off > 0; off >>= 1) {
    loss += __shfl_down(loss, off, 64);
    cnt += __shfl_down(cnt, off, 64);
  }

  __shared__ float sl[4], sc[4];
  int wave = threadIdx.x >> 6;
  int lane = threadIdx.x & 63;
  if (lane == 0) {
    sl[wave] = loss;
    sc[wave] = cnt;
  }
  __syncthreads();
  if (threadIdx.x == 0) {
    float L = sl[0] + sl[1] + sl[2] + sl[3];
    float Cn = sc[0] + sc[1] + sc[2] + sc[3];
    atomicAdd(ws, L);
    atomicAdd(ws + 1, Cn);
  }
}

__global__ void lms_final_kernel(const float* __restrict__ ws,
                                 float* __restrict__ out) {
  out[0] = ws[0] / ws[1];
}

extern "C" void kernel_launch(void* const* d_in, const int* in_sizes, int n_in,
                              void* d_out, int out_size, void* d_ws, size_t ws_size,
                              hipStream_t stream) {
  const float* logits = (const float*)d_in[0];
  const int* labels = (const int*)d_in[1];
  float* out = (float*)d_out;
  float* ws = (float*)d_ws;

  // ws[0] = loss sum, ws[1] = valid count (ws re-poisoned each call)
  hipMemsetAsync(ws, 0, 2 * sizeof(float), stream);

  int threads = 256;
  int quads = NPIX / 4;                 // 524288 threads
  int blocks = (quads + threads - 1) / threads;  // 2048
  lms_main_kernel<<<blocks, threads, 0, stream>>>(logits, labels, ws);
  lms_final_kernel<<<1, 1, 0, stream>>>(ws, out);
}